// Round 11
// baseline (20.522 us; speedup 1.0000x reference)
//
#include <hip/hip_runtime.h>

#define N    16384
#define M    64        // Fourier modes (lane = m-1)
#define JBC  64        // j-chunks per array (K1 grid.x)
#define JSL  256       // j's per chunk
#define K2B  128       // K2 blocks
#define I2   128       // i's per K2 block

// rank_i = 1 + N/2 + 0.5*sum_j tanh(5*(x_j - x_i))
// tanh(5d) = d/L + sum_m beta_m sin(pi*m*d/L), L=8, beta_m = pi/(40*sinh(pi^2 m/80))
// S_m = sum_j sin(w_m x_j), C_m = sum_j cos(w_m x_j) once; then
// rank_i = [8193 + Sx/16] - 1024*x_i + sum_m 0.5*beta_m*(cos(w_m x_i) S_m - sin(w_m x_i) C_m)
// v_sin/v_cos take REVOLUTIONS: rev = fract(m*x/16).

__device__ __forceinline__ double ald_d(const double* p) {
  return __hip_atomic_load(p, __ATOMIC_RELAXED, __HIP_MEMORY_SCOPE_AGENT);
}
__device__ __forceinline__ void ast_d(double* p, double v) {
  __hip_atomic_store(p, v, __ATOMIC_RELAXED, __HIP_MEMORY_SCOPE_AGENT);
}

__global__ __launch_bounds__(256) void k1_freq(
    const float* __restrict__ pred, const float* __restrict__ target,
    float* __restrict__ ps, float* __restrict__ pc, float* __restrict__ px,
    int* __restrict__ bar) {
  const int a   = blockIdx.y;               // 0 = pred, 1 = target
  const int jb  = blockIdx.x;               // 0..JBC-1
  const int tid = threadIdx.x;
  if (a == 0 && jb == 0 && tid == 0) bar[0] = 0;   // reset K2 finalize counter

  const float* __restrict__ x = a ? target : pred;
  __shared__ float xs[JSL];
  __shared__ float s4[4][M], c4[4][M];
  xs[tid] = x[jb * JSL + tid];
  __syncthreads();

  const int w = tid >> 6, lane = tid & 63;
  const float mf = (float)(lane + 1) * 0.0625f;    // m/(2L)
  const float* __restrict__ xh = xs + w * 64;
  float ss = 0.f, cc = 0.f;
  #pragma unroll 8
  for (int k = 0; k < 64; ++k) {
    float rev = __builtin_amdgcn_fractf(mf * xh[k]);
    ss += __builtin_amdgcn_sinf(rev);
    cc += __builtin_amdgcn_cosf(rev);
  }
  s4[w][lane] = ss; c4[w][lane] = cc;
  __syncthreads();
  if (w == 0) {
    float S = (s4[0][lane] + s4[1][lane]) + (s4[2][lane] + s4[3][lane]);
    float C = (c4[0][lane] + c4[1][lane]) + (c4[2][lane] + c4[3][lane]);
    ps[(a * M + lane) * JBC + jb] = S;             // [a][m][jb]
    pc[(a * M + lane) * JBC + jb] = C;
  } else if (w == 1) {                             // chunk x-sum (linear term)
    float t = (xs[lane] + xs[lane + 64]) + (xs[lane + 128] + xs[lane + 192]);
    #pragma unroll
    for (int off = 32; off; off >>= 1) t += __shfl_down(t, off);
    if (lane == 0) px[a * JBC + jb] = t;
  }
}

__global__ __launch_bounds__(256) void k2_rank(
    const float* __restrict__ pred, const float* __restrict__ target,
    const float* __restrict__ ps, const float* __restrict__ pc,
    const float* __restrict__ px, double* __restrict__ mom,
    int* __restrict__ bar, float* __restrict__ out) {
  const int tid = threadIdx.x, b = blockIdx.x;

  // issue xi load FIRST -- independent of K1 output, hides under coef reduce
  const int a  = tid >> 7;                         // array
  const int li = tid & 127;
  const float* __restrict__ xa = a ? target : pred;
  const float xi = xa[b * I2 + li];

  __shared__ float2 sCTS[2][M];
  __shared__ float  sK[2];
  __shared__ float  shT[2][M], shC[2][M];
  {
    const int which = tid >> 7;                    // 0: sin sums (ps), 1: cos (pc)
    const int aa = (tid >> 6) & 1;
    const int mm = tid & 63;
    const float4* __restrict__ row =
        (const float4*)((which ? pc : ps) + (aa * M + mm) * JBC);
    float4 a4 = {0.f, 0.f, 0.f, 0.f};
    #pragma unroll
    for (int q = 0; q < JBC / 4; ++q) {
      float4 v = row[q];
      a4.x += v.x; a4.y += v.y; a4.z += v.z; a4.w += v.w;
    }
    float s = (a4.x + a4.y) + (a4.z + a4.w);
    if (which) shC[aa][mm] = s; else shT[aa][mm] = s;
    if (tid < 2) {
      const float4* __restrict__ prow = (const float4*)(px + tid * JBC);
      float4 t4 = {0.f, 0.f, 0.f, 0.f};
      #pragma unroll
      for (int q = 0; q < JBC / 4; ++q) {
        float4 v = prow[q];
        t4.x += v.x; t4.y += v.y; t4.z += v.z; t4.w += v.w;
      }
      sK[tid] = 8193.0f + 0.0625f * ((t4.x + t4.y) + (t4.z + t4.w));
    }
  }
  __syncthreads();
  if (tid < 2 * M) {
    const int a2 = tid >> 6, m2 = tid & 63;
    const float t    = 0.123370055013617f * (float)(m2 + 1);       // pi^2*m/80
    const float e    = __expf(t);
    const float beta = 3.14159265358979f / (20.0f * (e - 1.0f / e)); // pi/(40 sinh t)
    sCTS[a2][m2] = make_float2(0.5f * beta * shT[a2][m2],
                               -0.5f * beta * shC[a2][m2]);
  }
  __syncthreads();

  float acc = 0.f;
  #pragma unroll 8
  for (int m = 1; m <= M; ++m) {
    const float2 c = sCTS[a][m - 1];
    float rev = __builtin_amdgcn_fractf((float)m * 0.0625f * xi);
    acc = fmaf(__builtin_amdgcn_cosf(rev), c.x, acc);
    acc = fmaf(__builtin_amdgcn_sinf(rev), c.y, acc);
  }
  __shared__ float rk[2][I2];
  rk[a][li] = sK[a] - 1024.0f * xi + acc;
  __syncthreads();

  if (tid < 64) {                                  // block moments, one wave
    double p0 = (double)rk[0][tid], p1 = (double)rk[0][tid + 64];
    double t0 = (double)rk[1][tid], t1 = (double)rk[1][tid + 64];
    double v[5] = {p0 + p1, t0 + t1, p0*p0 + p1*p1, t0*t0 + t1*t1, p0*t0 + p1*t1};
    #pragma unroll
    for (int off = 32; off; off >>= 1) {
      #pragma unroll
      for (int k = 0; k < 5; ++k) v[k] += __shfl_down(v[k], off);
    }
    if (tid == 0) {
      #pragma unroll
      for (int k = 0; k < 5; ++k) ast_d(&mom[b * 5 + k], v[k]);
    }
  }
  __syncthreads();

  __shared__ int lastFin;
  if (tid == 0) {
    __threadfence();                               // release mom stores
    int prev = __hip_atomic_fetch_add(&bar[0], 1, __ATOMIC_ACQ_REL,
                                      __HIP_MEMORY_SCOPE_AGENT);
    lastFin = (prev == K2B - 1);
  }
  __syncthreads();
  if (lastFin) {                                   // 2-wave finalize over 128 rows
    __shared__ double wsF[2][5];
    if (tid < 128) {
      double v[5];
      #pragma unroll
      for (int k = 0; k < 5; ++k) v[k] = ald_d(&mom[tid * 5 + k]);
      #pragma unroll
      for (int off = 32; off; off >>= 1) {
        #pragma unroll
        for (int k = 0; k < 5; ++k) v[k] += __shfl_down(v[k], off);
      }
      if ((tid & 63) == 0) {
        #pragma unroll
        for (int k = 0; k < 5; ++k) wsF[tid >> 6][k] = v[k];
      }
    }
    __syncthreads();
    if (tid == 0) {
      const double n  = (double)N;
      const double s0 = wsF[0][0] + wsF[1][0];
      const double s1 = wsF[0][1] + wsF[1][1];
      const double s2 = wsF[0][2] + wsF[1][2];
      const double s3 = wsF[0][3] + wsF[1][3];
      const double s4 = wsF[0][4] + wsF[1][4];
      const double mp = s0 / n, mt = s1 / n;
      const double cov  = s4 / n - mp * mt;
      const double varp = s2 / n - mp * mp;
      const double vart = s3 / n - mt * mt;
      const double corr = cov / (sqrt(varp + 1e-8) * sqrt(vart + 1e-8));
      out[0] = (float)(1.0 - corr);
    }
  }
}

extern "C" void kernel_launch(void* const* d_in, const int* in_sizes, int n_in,
                              void* d_out, int out_size, void* d_ws, size_t ws_size,
                              hipStream_t stream) {
  const float* pred   = (const float*)d_in[0];
  const float* target = (const float*)d_in[1];
  float* out = (float*)d_out;

  // ws: mom[K2B*5] f64 | ps[2*M*JBC] f32 | pc[2*M*JBC] f32 | px[2*JBC] f32 | bar[1]
  double* mom = (double*)d_ws;
  float*  ps  = (float*)((char*)d_ws + K2B * 5 * sizeof(double));
  float*  pc  = ps + 2 * M * JBC;
  float*  px  = pc + 2 * M * JBC;
  int*    bar = (int*)(px + 2 * JBC);

  k1_freq<<<dim3(JBC, 2), 256, 0, stream>>>(pred, target, ps, pc, px, bar);
  k2_rank<<<K2B, 256, 0, stream>>>(pred, target, ps, pc, px, mom, bar, out);
}

// Round 12
// 18.950 us; speedup vs baseline: 1.0829x; 1.0829x over previous
//
#include <hip/hip_runtime.h>

#define N    16384
#define M    64        // Fourier modes (lane = m-1)
#define JBC  32        // j-chunks per array (K1 grid.x)
#define JSL  512       // j's per chunk
#define K2B  64        // K2 blocks
#define I2   256       // i's per K2 block

// rank_i = 1 + N/2 + 0.5*sum_j tanh(5*(x_j - x_i))
// tanh(5d) = d/L + sum_m beta_m sin(pi*m*d/L), L=8, beta_m = pi/(40*sinh(pi^2 m/80))
// S_m = sum_j sin(w_m x_j), C_m = sum_j cos(w_m x_j) once; then
// rank_i = [8193 + Sx/16] - 1024*x_i + sum_m 0.5*beta_m*(cos(w_m x_i) S_m - sin(w_m x_i) C_m)
// v_sin/v_cos take REVOLUTIONS: rev = fract(m*x/16).

__device__ __forceinline__ double ald_d(const double* p) {
  return __hip_atomic_load(p, __ATOMIC_RELAXED, __HIP_MEMORY_SCOPE_AGENT);
}
__device__ __forceinline__ void ast_d(double* p, double v) {
  __hip_atomic_store(p, v, __ATOMIC_RELAXED, __HIP_MEMORY_SCOPE_AGENT);
}

__global__ __launch_bounds__(256) void k1_freq(
    const float* __restrict__ pred, const float* __restrict__ target,
    float* __restrict__ ps, float* __restrict__ pc, float* __restrict__ px,
    int* __restrict__ bar) {
  const int a   = blockIdx.y;               // 0 = pred, 1 = target
  const int jb  = blockIdx.x;               // 0..JBC-1
  const int tid = threadIdx.x;
  if (a == 0 && jb == 0 && tid == 0) bar[0] = 0;   // reset K2 finalize counter

  const float* __restrict__ x = a ? target : pred;
  __shared__ float xs[JSL];
  __shared__ float s4[4][M], c4[4][M];
  xs[tid]       = x[jb * JSL + tid];
  xs[tid + 256] = x[jb * JSL + 256 + tid];
  __syncthreads();

  const int w = tid >> 6, lane = tid & 63;
  const float mf = (float)(lane + 1) * 0.0625f;    // m/(2L)
  const float* __restrict__ xh = xs + w * 128;
  float ss = 0.f, cc = 0.f;
  #pragma unroll 8
  for (int k = 0; k < 128; ++k) {
    float rev = __builtin_amdgcn_fractf(mf * xh[k]);
    ss += __builtin_amdgcn_sinf(rev);
    cc += __builtin_amdgcn_cosf(rev);
  }
  s4[w][lane] = ss; c4[w][lane] = cc;
  __syncthreads();
  if (w == 0) {
    float S = (s4[0][lane] + s4[1][lane]) + (s4[2][lane] + s4[3][lane]);
    float C = (c4[0][lane] + c4[1][lane]) + (c4[2][lane] + c4[3][lane]);
    ps[(a * M + lane) * JBC + jb] = S;             // [a][m][jb]
    pc[(a * M + lane) * JBC + jb] = C;
  } else if (w == 1) {                             // chunk x-sum (linear term)
    float t = 0.f;
    #pragma unroll
    for (int k = 0; k < 8; ++k) t += xs[lane + 64 * k];
    #pragma unroll
    for (int off = 32; off; off >>= 1) t += __shfl_down(t, off);
    if (lane == 0) px[a * JBC + jb] = t;
  }
}

__global__ __launch_bounds__(256) void k2_rank(
    const float* __restrict__ pred, const float* __restrict__ target,
    const float* __restrict__ ps, const float* __restrict__ pc,
    const float* __restrict__ px, double* __restrict__ mom,
    int* __restrict__ bar, float* __restrict__ out) {
  const int tid = threadIdx.x, b = blockIdx.x;

  __shared__ float2 sCTS[2][M];
  __shared__ float  sK[2];
  __shared__ float  shT[2][M], shC[2][M];
  {
    const int which = tid >> 7;                    // 0: sin sums (ps), 1: cos (pc)
    const int aa = (tid >> 6) & 1;
    const int mm = tid & 63;
    const float4* __restrict__ row =
        (const float4*)((which ? pc : ps) + (aa * M + mm) * JBC);
    float4 a4 = {0.f, 0.f, 0.f, 0.f};
    #pragma unroll
    for (int q = 0; q < JBC / 4; ++q) {
      float4 v = row[q];
      a4.x += v.x; a4.y += v.y; a4.z += v.z; a4.w += v.w;
    }
    float s = (a4.x + a4.y) + (a4.z + a4.w);
    if (which) shC[aa][mm] = s; else shT[aa][mm] = s;
    if (tid < 2) {
      const float4* __restrict__ prow = (const float4*)(px + tid * JBC);
      float4 t4 = {0.f, 0.f, 0.f, 0.f};
      #pragma unroll
      for (int q = 0; q < JBC / 4; ++q) {
        float4 v = prow[q];
        t4.x += v.x; t4.y += v.y; t4.z += v.z; t4.w += v.w;
      }
      sK[tid] = 8193.0f + 0.0625f * ((t4.x + t4.y) + (t4.z + t4.w));
    }
  }
  __syncthreads();
  if (tid < 2 * M) {
    const int a2 = tid >> 6, m2 = tid & 63;
    const float t    = 0.123370055013617f * (float)(m2 + 1);       // pi^2*m/80
    const float e    = __expf(t);
    const float beta = 3.14159265358979f / (20.0f * (e - 1.0f / e)); // pi/(40 sinh t)
    sCTS[a2][m2] = make_float2(0.5f * beta * shT[a2][m2],
                               -0.5f * beta * shC[a2][m2]);
  }
  __syncthreads();

  const int a  = tid >> 7;                         // array
  const int li = tid & 127;
  const float* __restrict__ xa = a ? target : pred;
  __shared__ float rk[2][I2];
  #pragma unroll
  for (int p2 = 0; p2 < 2; ++p2) {
    const int i = b * I2 + p2 * 128 + li;
    const float xi = xa[i];
    float acc = 0.f;
    #pragma unroll 8
    for (int m = 1; m <= M; ++m) {
      const float2 c = sCTS[a][m - 1];
      float rev = __builtin_amdgcn_fractf((float)m * 0.0625f * xi);
      acc = fmaf(__builtin_amdgcn_cosf(rev), c.x, acc);
      acc = fmaf(__builtin_amdgcn_sinf(rev), c.y, acc);
    }
    rk[a][p2 * 128 + li] = sK[a] - 1024.0f * xi + acc;
  }
  __syncthreads();

  __shared__ double wsum[2][5];
  if (tid < 128) {                                 // block moments, 2 waves
    double p0 = (double)rk[0][tid],       t0 = (double)rk[1][tid];
    double p1 = (double)rk[0][tid + 128], t1 = (double)rk[1][tid + 128];
    double v[5] = {p0 + p1, t0 + t1, p0*p0 + p1*p1, t0*t0 + t1*t1, p0*t0 + p1*t1};
    #pragma unroll
    for (int off = 32; off; off >>= 1) {
      #pragma unroll
      for (int k = 0; k < 5; ++k) v[k] += __shfl_down(v[k], off);
    }
    if ((tid & 63) == 0) {
      #pragma unroll
      for (int k = 0; k < 5; ++k) wsum[tid >> 6][k] = v[k];
    }
  }
  __syncthreads();

  __shared__ int lastFin;
  if (tid == 0) {
    #pragma unroll
    for (int k = 0; k < 5; ++k) ast_d(&mom[b * 5 + k], wsum[0][k] + wsum[1][k]);
    __threadfence();                               // release (cheap; R6-proven)
    int prev = __hip_atomic_fetch_add(&bar[0], 1, __ATOMIC_ACQ_REL,
                                      __HIP_MEMORY_SCOPE_AGENT);
    lastFin = (prev == K2B - 1);
  }
  __syncthreads();
  if (lastFin && tid < 64) {                       // single-wave finalize
    double v[5];
    #pragma unroll
    for (int k = 0; k < 5; ++k) v[k] = ald_d(&mom[tid * 5 + k]);
    #pragma unroll
    for (int off = 32; off; off >>= 1) {
      #pragma unroll
      for (int k = 0; k < 5; ++k) v[k] += __shfl_down(v[k], off);
    }
    if (tid == 0) {
      const double n  = (double)N;
      const double mp = v[0] / n;
      const double mt = v[1] / n;
      const double cov  = v[4] / n - mp * mt;
      const double varp = v[2] / n - mp * mp;
      const double vart = v[3] / n - mt * mt;
      const double corr = cov / (sqrt(varp + 1e-8) * sqrt(vart + 1e-8));
      out[0] = (float)(1.0 - corr);
    }
  }
}

extern "C" void kernel_launch(void* const* d_in, const int* in_sizes, int n_in,
                              void* d_out, int out_size, void* d_ws, size_t ws_size,
                              hipStream_t stream) {
  const float* pred   = (const float*)d_in[0];
  const float* target = (const float*)d_in[1];
  float* out = (float*)d_out;

  // ws: mom[K2B*5] f64 | ps[2*M*JBC] f32 | pc[2*M*JBC] f32 | px[2*JBC] f32 | bar[1]
  double* mom = (double*)d_ws;
  float*  ps  = (float*)((char*)d_ws + K2B * 5 * sizeof(double));
  float*  pc  = ps + 2 * M * JBC;
  float*  px  = pc + 2 * M * JBC;
  int*    bar = (int*)(px + 2 * JBC);

  k1_freq<<<dim3(JBC, 2), 256, 0, stream>>>(pred, target, ps, pc, px, bar);
  k2_rank<<<K2B, 256, 0, stream>>>(pred, target, ps, pc, px, mom, bar, out);
}